// Round 2
// baseline (387.446 us; speedup 1.0000x reference)
//
#include <hip/hip_runtime.h>

// ---------------------------------------------------------------------------
// AdversarialHead: fwd net (cf ++ one_hot) @ W1 @ W2, inv net softmax heads.
// I/O dtype: fp32 (reference is jnp.float32; bf16-grade tolerance only).
// Internally: bf16 MFMA with fp32 accumulate; hbuf kept bf16 in ws.
//
//   h[m,140]    = cf[m,:] @ W1[0:512,:] + W1[512+s0] + W1[512+s1] + W1[512+s2] + b1
//   pred[m,256] = h[m,:] @ W2 + b2
//   L[m,18]     = cf[m,:] @ Wc[0:512,:] + nf[m,:] @ Wc[512:1024,:]  (bias=0, cancels)
//   a*(f,a,j)   = softmax over a (32 agents per frame);  m = f*32+a, M = 65536
// ---------------------------------------------------------------------------

using bf16x8  = __attribute__((ext_vector_type(8))) __bf16;
using floatx4 = __attribute__((ext_vector_type(4))) float;

__device__ __forceinline__ unsigned short f2bf(float f) {
    unsigned int u = __float_as_uint(f);
    unsigned int r = (u + 0x7fffu + ((u >> 16) & 1u)) >> 16;
    return (unsigned short)r;
}
__device__ __forceinline__ ushort4 cvt4(const float* __restrict__ p) {
    float4 v = *(const float4*)p;
    ushort4 o;
    o.x = f2bf(v.x); o.y = f2bf(v.y); o.z = f2bf(v.z); o.w = f2bf(v.w);
    return o;
}

#define M_ROWS 65536
#define HP 160            // padded K for gemm2 (140 -> 160)

// ws element offsets (bf16 elements)
#define OFF_W1T 0                      // [144][512]
#define OFF_W2T (OFF_W1T + 144*512)    // [256][160]
#define OFF_WCT (OFF_W2T + 256*160)    // [32][1024]
#define OFF_H   (OFF_WCT + 32*1024)    // [65536][160]

// d_out element offsets (fp32 elements)
#define OFF_A0 ((size_t)16777216)
#define OFF_A1 ((size_t)17301504)
#define OFF_A2 ((size_t)17694720)

// ---------------------------------------------------------------------------
// Repack weights fp32 -> bf16, transposed + zero-padded.
__global__ __launch_bounds__(256) void prep_kernel(
    const float* __restrict__ W1,   // [530][140]
    const float* __restrict__ W2,   // [140][256]
    const float* __restrict__ Wi0,  // [1024][8]
    const float* __restrict__ Wi1,  // [1024][6]
    const float* __restrict__ Wi2,  // [1024][4]
    unsigned short* __restrict__ ws)
{
    unsigned short* W1T = ws + OFF_W1T;
    unsigned short* W2T = ws + OFF_W2T;
    unsigned short* WcT = ws + OFF_WCT;
    const int total = 144*512 + 256*160 + 32*1024;
    for (int idx = blockIdx.x * 256 + threadIdx.x; idx < total; idx += gridDim.x * 256) {
        if (idx < 144*512) {
            int j = idx >> 9, k = idx & 511;          // W1T[j][k] = W1[k][j]
            W1T[idx] = (j < 140) ? f2bf(W1[k*140 + j]) : (unsigned short)0;
        } else if (idx < 144*512 + 256*160) {
            int i2 = idx - 144*512;
            int n = i2 / 160, k = i2 - n*160;         // W2T[n][k] = W2[k][n]
            W2T[i2] = (k < 140) ? f2bf(W2[k*256 + n]) : (unsigned short)0;
        } else {
            int i3 = idx - (144*512 + 256*160);
            int j = i3 >> 10, k = i3 & 1023;          // WcT[j][k]
            unsigned short v = 0;
            if (j < 8)       v = f2bf(Wi0[k*8 + j]);
            else if (j < 14) v = f2bf(Wi1[k*6 + (j - 8)]);
            else if (j < 18) v = f2bf(Wi2[k*4 + (j - 14)]);
            WcT[i3] = v;
        }
    }
}

// ---------------------------------------------------------------------------
// GEMM1: h[64 rows][144] = cf-tile @ W1a  (+ one-hot rows of W1 + b1, fp32)
// block: 256 thr (4 waves), wave w owns rows 16w..16w+15. K=512 in 8 chunks.
__global__ __launch_bounds__(256) void gemm1_kernel(
    const float* __restrict__ cf,
    const int* __restrict__ actions,          // [2048][3][32]
    const float* __restrict__ W1,             // rows 512..529 for one-hot add
    const float* __restrict__ b1,
    const unsigned short* __restrict__ W1T,   // [144][512] bf16
    unsigned short* __restrict__ hbuf)        // [65536][160] bf16
{
    __shared__ alignas(16) __bf16 As[64 * 72];    // stride 72: 16B rows, 2-way banks
    __shared__ alignas(16) __bf16 Bs[144 * 72];
    __shared__ float Us[18 * 144];                // one-hot rows of W1 (fp32, padded)
    __shared__ float b1s[144];
    __shared__ int   sidx[64 * 3];

    const int t = threadIdx.x;
    const int w = t >> 6, l = t & 63;
    const int m0 = blockIdx.x * 64;

    for (int i = t; i < 18 * 144; i += 256) {
        int s = i / 144, j = i - s * 144;
        Us[i] = (j < 140) ? W1[(512 + s) * 140 + j] : 0.f;
    }
    if (t < 144) b1s[t] = (t < 140) ? b1[t] : 0.f;
    if (t < 192) {
        int r = t / 3, tt = t - r * 3;
        int m = m0 + r, f = m >> 5, a = m & 31;
        int start = (tt == 0) ? 0 : (tt == 1 ? 8 : 14);
        sidx[t] = actions[f * 96 + tt * 32 + a] + start;
    }

    floatx4 acc[9];
#pragma unroll
    for (int n = 0; n < 9; ++n) { acc[n][0]=0.f; acc[n][1]=0.f; acc[n][2]=0.f; acc[n][3]=0.f; }

    for (int kc = 0; kc < 8; ++kc) {
#pragma unroll
        for (int it = 0; it < 4; ++it) {          // A tile: 64x64, fp32->bf16
            int idx = t + it * 256;
            int r = idx >> 4, c4 = idx & 15;
            *(ushort4*)(&As[r * 72 + c4 * 4]) =
                cvt4(cf + (size_t)(m0 + r) * 512 + kc * 64 + c4 * 4);
        }
#pragma unroll
        for (int it = 0; it < 5; ++it) {          // B tile: 144x64 bf16 (ws)
            int idx = t + it * 256;
            if (idx < 1152) {
                int j = idx >> 3, c8 = idx & 7;
                *(uint4*)(&Bs[j * 72 + c8 * 8]) =
                    *(const uint4*)(W1T + (size_t)j * 512 + kc * 64 + c8 * 8);
            }
        }
        __syncthreads();
        const int ao = (w * 16 + (l & 15)) * 72 + ((l >> 4) << 3);
#pragma unroll
        for (int ks = 0; ks < 2; ++ks) {
            bf16x8 a = *(const bf16x8*)&As[ao + ks * 32];
#pragma unroll
            for (int n = 0; n < 9; ++n) {
                bf16x8 b = *(const bf16x8*)&Bs[(n * 16 + (l & 15)) * 72 + ks * 32 + ((l >> 4) << 3)];
                acc[n] = __builtin_amdgcn_mfma_f32_16x16x32_bf16(a, b, acc[n], 0, 0, 0);
            }
        }
        __syncthreads();
    }

    // epilogue: C/D layout col=lane&15, row=(lane>>4)*4+i
    const int col = l & 15;
    const int r0 = w * 16 + ((l >> 4) << 2);
#pragma unroll
    for (int i = 0; i < 4; ++i) {
        int r = r0 + i;
        int s0 = sidx[r * 3 + 0], s1 = sidx[r * 3 + 1], s2 = sidx[r * 3 + 2];
        size_t rowbase = (size_t)(m0 + r) * HP;
#pragma unroll
        for (int n = 0; n < 9; ++n) {
            int j = n * 16 + col;
            float v = acc[n][i] + b1s[j]
                    + Us[s0 * 144 + j] + Us[s1 * 144 + j] + Us[s2 * 144 + j];
            hbuf[rowbase + j] = f2bf(v);
        }
    }
    {   // zero pad cols 144..159 (so gemm2 K-loop reads zeros)
        int r = t >> 2, g = t & 3;
        ushort4 z; z.x = z.y = z.z = z.w = 0;
        *(ushort4*)(hbuf + (size_t)(m0 + r) * HP + 144 + g * 4) = z;
    }
}

// ---------------------------------------------------------------------------
// GEMM2: pred[64][256] = h-tile[64][160] @ W2T^T + b2   (fp32 out)
__global__ __launch_bounds__(256) void gemm2_kernel(
    const unsigned short* __restrict__ hbuf,
    const float* __restrict__ b2,
    const unsigned short* __restrict__ W2T,   // [256][160] bf16
    float* __restrict__ outp)                 // [65536][256] fp32
{
    __shared__ alignas(16) __bf16 hs[64 * 56];    // stride 56: 16B rows, 2-way banks
    __shared__ alignas(16) __bf16 Ws[256 * 56];
    __shared__ float b2s[256];

    const int t = threadIdx.x;
    const int w = t >> 6, l = t & 63;
    const int m0 = blockIdx.x * 64;

    b2s[t] = b2[t];

    floatx4 acc[16];
#pragma unroll
    for (int n = 0; n < 16; ++n) { acc[n][0]=0.f; acc[n][1]=0.f; acc[n][2]=0.f; acc[n][3]=0.f; }

    for (int kc = 0; kc < 5; ++kc) {              // K = 160 in chunks of 32
        {   // h tile: 64x32 bf16
            int r = t >> 2, c8 = t & 3;
            *(uint4*)(&hs[r * 56 + c8 * 8]) =
                *(const uint4*)(hbuf + (size_t)(m0 + r) * HP + kc * 32 + c8 * 8);
        }
#pragma unroll
        for (int it = 0; it < 4; ++it) {          // W2 chunk: 256x32 bf16
            int idx = t + it * 256;
            int n = idx >> 2, c8 = idx & 3;
            *(uint4*)(&Ws[n * 56 + c8 * 8]) =
                *(const uint4*)(W2T + (size_t)n * 160 + kc * 32 + c8 * 8);
        }
        __syncthreads();
        bf16x8 a = *(const bf16x8*)&hs[(w * 16 + (l & 15)) * 56 + ((l >> 4) << 3)];
#pragma unroll
        for (int n = 0; n < 16; ++n) {
            bf16x8 b = *(const bf16x8*)&Ws[(n * 16 + (l & 15)) * 56 + ((l >> 4) << 3)];
            acc[n] = __builtin_amdgcn_mfma_f32_16x16x32_bf16(a, b, acc[n], 0, 0, 0);
        }
        __syncthreads();
    }

    const int col = l & 15;
    const int r0 = w * 16 + ((l >> 4) << 2);
#pragma unroll
    for (int n = 0; n < 16; ++n) {
        int j = n * 16 + col;
        float bj = b2s[j];
#pragma unroll
        for (int i = 0; i < 4; ++i)
            outp[(size_t)(m0 + r0 + i) * 256 + j] = acc[n][i] + bj;
    }
}

// ---------------------------------------------------------------------------
// Inverse heads: logits[64][18] = [cf|nf] @ Wc, softmax over the 32 agents of
// each of the block's 2 frames. Bias dropped (zeros; also cancels in softmax).
__global__ __launch_bounds__(256) void inv_kernel(
    const float* __restrict__ cf,
    const float* __restrict__ nf,
    const unsigned short* __restrict__ WcT,   // [32][1024] bf16
    float* __restrict__ out_base)
{
    __shared__ alignas(16) __bf16 As[64 * 72];
    __shared__ alignas(16) __bf16 Bs[32 * 72];
    __shared__ float Ls[64 * 20];
    __shared__ float rmx[36], rsc[36];

    const int t = threadIdx.x;
    const int w = t >> 6, l = t & 63;
    const int m0 = blockIdx.x * 64;

    floatx4 acc[2];
#pragma unroll
    for (int n = 0; n < 2; ++n) { acc[n][0]=0.f; acc[n][1]=0.f; acc[n][2]=0.f; acc[n][3]=0.f; }

    for (int kc = 0; kc < 16; ++kc) {             // K = 1024: cf then nf
        const float* src = (kc < 8) ? cf : nf;
        const int ko = (kc & 7) * 64;
#pragma unroll
        for (int it = 0; it < 4; ++it) {          // A tile: 64x64, fp32->bf16
            int idx = t + it * 256;
            int r = idx >> 4, c4 = idx & 15;
            *(ushort4*)(&As[r * 72 + c4 * 4]) =
                cvt4(src + (size_t)(m0 + r) * 512 + ko + c4 * 4);
        }
        {
            int j = t >> 3, c8 = t & 7;           // 32x64 bf16 (ws)
            *(uint4*)(&Bs[j * 72 + c8 * 8]) =
                *(const uint4*)(WcT + (size_t)j * 1024 + kc * 64 + c8 * 8);
        }
        __syncthreads();
#pragma unroll
        for (int ks = 0; ks < 2; ++ks) {
            bf16x8 a = *(const bf16x8*)&As[(w * 16 + (l & 15)) * 72 + ks * 32 + ((l >> 4) << 3)];
#pragma unroll
            for (int n = 0; n < 2; ++n) {
                bf16x8 b = *(const bf16x8*)&Bs[(n * 16 + (l & 15)) * 72 + ks * 32 + ((l >> 4) << 3)];
                acc[n] = __builtin_amdgcn_mfma_f32_16x16x32_bf16(a, b, acc[n], 0, 0, 0);
            }
        }
        __syncthreads();
    }

    const int col = l & 15;
    const int r0 = w * 16 + ((l >> 4) << 2);
#pragma unroll
    for (int n = 0; n < 2; ++n) {
        int j = n * 16 + col;
        if (j < 18) {
#pragma unroll
            for (int i = 0; i < 4; ++i) Ls[(r0 + i) * 20 + j] = acc[n][i];
        }
    }
    __syncthreads();

    if (t < 36) {                                  // per (frame-in-block, j): max & sum
        int fr = t / 18, j = t - fr * 18;
        float mx = -1e30f;
        for (int a = 0; a < 32; ++a) mx = fmaxf(mx, Ls[(fr * 32 + a) * 20 + j]);
        float s = 0.f;
        for (int a = 0; a < 32; ++a) s += expf(Ls[(fr * 32 + a) * 20 + j] - mx);
        rmx[t] = mx; rsc[t] = 1.f / s;
    }
    __syncthreads();

#pragma unroll
    for (int it = 0; it < 5; ++it) {               // 64*18 = 1152 outputs
        int idx = t + it * 256;
        if (idx < 1152) {
            int r = idx / 18, j = idx - r * 18;
            int fr = r >> 5;
            float v = expf(Ls[r * 20 + j] - rmx[fr * 18 + j]) * rsc[fr * 18 + j];
            int m = m0 + r;
            size_t o;
            if (j < 8)       o = OFF_A0 + (size_t)m * 8 + j;
            else if (j < 14) o = OFF_A1 + (size_t)m * 6 + (j - 8);
            else             o = OFF_A2 + (size_t)m * 4 + (j - 14);
            out_base[o] = v;
        }
    }
}

// ---------------------------------------------------------------------------
extern "C" void kernel_launch(void* const* d_in, const int* in_sizes, int n_in,
                              void* d_out, int out_size, void* d_ws, size_t ws_size,
                              hipStream_t stream)
{
    const float* cf  = (const float*)d_in[0];
    const float* nf  = (const float*)d_in[1];
    const int*   act = (const int*)d_in[2];
    const float* W1  = (const float*)d_in[3];
    const float* b1  = (const float*)d_in[4];
    const float* W2  = (const float*)d_in[5];
    const float* b2  = (const float*)d_in[6];
    const float* Wi0 = (const float*)d_in[7];
    const float* Wi1 = (const float*)d_in[9];
    const float* Wi2 = (const float*)d_in[11];

    unsigned short* ws   = (unsigned short*)d_ws;
    unsigned short* W1T  = ws + OFF_W1T;
    unsigned short* W2T  = ws + OFF_W2T;
    unsigned short* WcT  = ws + OFF_WCT;
    unsigned short* hbuf = ws + OFF_H;
    float* outp = (float*)d_out;

    hipLaunchKernelGGL(prep_kernel, dim3(256), dim3(256), 0, stream,
                       W1, W2, Wi0, Wi1, Wi2, ws);
    hipLaunchKernelGGL(gemm1_kernel, dim3(M_ROWS / 64), dim3(256), 0, stream,
                       cf, act, W1, b1, W1T, hbuf);
    hipLaunchKernelGGL(gemm2_kernel, dim3(M_ROWS / 64), dim3(256), 0, stream,
                       hbuf, b2, W2T, outp);
    hipLaunchKernelGGL(inv_kernel, dim3(M_ROWS / 64), dim3(256), 0, stream,
                       cf, nf, WcT, outp);
}